// Round 1
// 379.613 us; speedup vs baseline: 1.0378x; 1.0378x over previous
//
#include <hip/hip_runtime.h>
#include <hip/hip_bf16.h>
#include <stdint.h>
#include <stddef.h>

// ---------------------------------------------------------------------------
// TSPEnergyFunction: out[i,j] = (1 - cos(x1_i, x2_j)) + 0.01 * mi
// mi = mean(t_xy) - (mean(exp(t_sh)) + ln 2) from a MINE critic.
// f32 in/out; internally bf16 MFMA GEMMs.
// R1 changes vs 393.96us baseline:
//  - k_dist: reg-staged padded-LDS -> global_load_lds width-16, linear LDS
//    (m97 structure, measured 874 vs 646 TF for reg-staging at 128^2 tile).
//  - k_finalize folded into k_dist epilogue (reads accum directly).
//  - k_prep_weights merged into k_prep_rows (one launch).
//  - k_compress / k_critic widened to 256 blocks (64 rows/block) for TLP.
// ---------------------------------------------------------------------------

typedef __attribute__((ext_vector_type(8))) short bf16x8;
typedef __attribute__((ext_vector_type(4))) float f32x4;

__device__ __forceinline__ float bf2f(unsigned short u) {
  union { unsigned int i; float f; } a; a.i = ((unsigned int)u) << 16; return a.f;
}
__device__ __forceinline__ unsigned short f2bf(float f) {
  union { float f; unsigned int i; } a; a.f = f;
  unsigned int r = a.i + 0x7fffu + ((a.i >> 16) & 1u);  // RNE
  return (unsigned short)(r >> 16);
}

__device__ __forceinline__ void gl16(const unsigned short* g, unsigned short* l) {
  __builtin_amdgcn_global_load_lds(
      (const __attribute__((address_space(1))) void*)g,
      (__attribute__((address_space(3))) void*)l, 16, 0, 0);
}

#define NROWS 8192
#define DDIM 256
#define CDIM 128
#define HDIM 128

// ---------------------------------------------------------------------------
// 1) Prep (merged): all blocks convert rows f32->bf16 + inverse norms;
//    blocks < 32 additionally transpose weights to bf16 and init scalars.
// ---------------------------------------------------------------------------
__global__ __launch_bounds__(256) void k_prep(
    const float* __restrict__ x1, const float* __restrict__ x2,
    const float* __restrict__ Wc, const float* __restrict__ bc,
    const float* __restrict__ W1, const float* __restrict__ b1,
    const float* __restrict__ W2, const float* __restrict__ b2,
    const float* __restrict__ W3, const float* __restrict__ b3,
    unsigned short* __restrict__ xall,
    float* __restrict__ inva, float* __restrict__ invb,
    unsigned short* __restrict__ WcT, unsigned short* __restrict__ W1T,
    unsigned short* __restrict__ W2T, float* __restrict__ fsmall,
    float* __restrict__ accum) {
  int gtid = blockIdx.x * 256 + threadIdx.x;
  int wv = gtid >> 6;            // 0..16383
  int lane = threadIdx.x & 63;
  int first = (wv < NROWS);
  const float* src = first ? x1 : x2;
  float* invp = first ? inva : invb;
  int row = first ? wv : wv - NROWS;
  float4 v = *((const float4*)(src + (size_t)row * DDIM) + lane);
  ushort4 o;
  o.x = f2bf(v.x); o.y = f2bf(v.y); o.z = f2bf(v.z); o.w = f2bf(v.w);
  *((ushort4*)(xall + (size_t)wv * DDIM) + lane) = o;
  float ss = v.x * v.x + v.y * v.y + v.z * v.z + v.w * v.w;
#pragma unroll
  for (int off = 32; off > 0; off >>= 1) ss += __shfl_xor(ss, off, 64);
  if (lane == 0) invp[row] = 1.0f / fmaxf(sqrtf(ss), 1e-8f);

  if (blockIdx.x < 32) {
    int t = blockIdx.x * 256 + threadIdx.x;
    const int T = 32 * 256;
    for (int i = t; i < DDIM * CDIM; i += T) {
      int k = i >> 7, n = i & 127;          // W[k][n] row-major [256][128]
      WcT[n * DDIM + k] = f2bf(Wc[i]);
      W1T[n * DDIM + k] = f2bf(W1[i]);
    }
    for (int i = t; i < HDIM * HDIM; i += T) {
      int k = i >> 7, n = i & 127;
      W2T[n * HDIM + k] = f2bf(W2[i]);
    }
    if (blockIdx.x == 0) {
      int tt = threadIdx.x;
      if (tt < 128) {
        fsmall[tt]       = bc[tt];
        fsmall[128 + tt] = b1[tt];
        fsmall[256 + tt] = b2[tt];
        fsmall[384 + tt] = W3[tt];
      }
      if (tt == 0) {
        fsmall[512] = b3[0];
        accum[0] = 0.0f; accum[1] = 0.0f;
      }
    }
  }
}

// ---------------------------------------------------------------------------
// 2) Compressor: xc[v] = xall[v] @ Wc + bc, bf16 out.
//    256 blocks x 64 rows (16 rows/wave) for full-GPU coverage.
// ---------------------------------------------------------------------------
__global__ __launch_bounds__(256) void k_compress(
    const unsigned short* __restrict__ xall,
    const unsigned short* __restrict__ WcT,
    const float* __restrict__ fsmall,
    unsigned short* __restrict__ xc) {
  int lane = threadIdx.x & 63, wave = threadIdx.x >> 6;
  int lm = lane & 15, lq = lane >> 4;
  int r0 = blockIdx.x * 64 + wave * 16;

  f32x4 acc[8];
#pragma unroll
  for (int b = 0; b < 8; ++b) acc[b] = (f32x4)(0.0f);

  for (int ks = 0; ks < 8; ++ks) {
    int k = ks * 32 + lq * 8;
    bf16x8 a = *(const bf16x8*)(xall + (size_t)(r0 + lm) * DDIM + k);
    bf16x8 b[8];
#pragma unroll
    for (int nt = 0; nt < 8; ++nt)
      b[nt] = *(const bf16x8*)(WcT + (size_t)(nt * 16 + lm) * DDIM + k);
#pragma unroll
    for (int nt = 0; nt < 8; ++nt)
      acc[nt] = __builtin_amdgcn_mfma_f32_16x16x32_bf16(a, b[nt], acc[nt], 0, 0, 0);
  }

  int row = r0 + lq * 4;
#pragma unroll
  for (int nt = 0; nt < 8; ++nt) {
    int col = nt * 16 + lm;
    float bcv = fsmall[col];
#pragma unroll
    for (int r = 0; r < 4; ++r)
      xc[(size_t)(row + r) * CDIM + col] = f2bf(acc[nt][r] + bcv);
  }
}

// ---------------------------------------------------------------------------
// 3) Critic: 16384 virtual rows (first 8192 joint, last 8192 shuffled).
//    256 blocks x 64 vrows (16/wave); accumulate sum(t)/sum(exp(t)).
// ---------------------------------------------------------------------------
__global__ __launch_bounds__(256) void k_critic(
    const unsigned short* __restrict__ xc, const int* __restrict__ perm,
    const unsigned short* __restrict__ W1T, const unsigned short* __restrict__ W2T,
    const float* __restrict__ fsmall, float* __restrict__ accum) {
  __shared__ __attribute__((aligned(16))) unsigned short h1buf[4][16][136];
  const float* b1 = fsmall + 128;
  const float* b2 = fsmall + 256;
  const float* W3 = fsmall + 384;
  int lane = threadIdx.x & 63, wave = threadIdx.x >> 6;
  int lm = lane & 15, lq = lane >> 4;
  int v0 = blockIdx.x * 64 + wave * 16;
  bool shuffled = (blockIdx.x * 64 >= NROWS);   // uniform per block

  f32x4 acc[8];
#pragma unroll
  for (int b = 0; b < 8; ++b) acc[b] = (f32x4)(0.0f);

  // layer 1: K = 256 (two 128-halves of z)
  for (int ks = 0; ks < 8; ++ks) {
    int k = ks * 32 + lq * 8;
    int i = (v0 + lm) & (NROWS - 1);
    const unsigned short* zp;
    if (k < CDIM) {
      zp = xc + (size_t)i * CDIM + k;
    } else {
      int j = shuffled ? perm[i] : i;
      zp = xc + (size_t)(NROWS + j) * CDIM + (k - CDIM);
    }
    bf16x8 a = *(const bf16x8*)zp;
    bf16x8 b[8];
#pragma unroll
    for (int nt = 0; nt < 8; ++nt)
      b[nt] = *(const bf16x8*)(W1T + (size_t)(nt * 16 + lm) * DDIM + k);
#pragma unroll
    for (int nt = 0; nt < 8; ++nt)
      acc[nt] = __builtin_amdgcn_mfma_f32_16x16x32_bf16(a, b[nt], acc[nt], 0, 0, 0);
  }

  // h1 = relu(acc + b1) -> LDS (per-wave buffer)
#pragma unroll
  for (int nt = 0; nt < 8; ++nt) {
    int col = nt * 16 + lm;
    float bv = b1[col];
#pragma unroll
    for (int r = 0; r < 4; ++r)
      h1buf[wave][lq * 4 + r][col] = f2bf(fmaxf(acc[nt][r] + bv, 0.0f));
  }
  __syncthreads();

  // layer 2: K = 128
  f32x4 acc2[8];
#pragma unroll
  for (int b = 0; b < 8; ++b) acc2[b] = (f32x4)(0.0f);
  for (int ks = 0; ks < 4; ++ks) {
    int k = ks * 32 + lq * 8;
    bf16x8 a = *(const bf16x8*)&h1buf[wave][lm][k];
    bf16x8 b[8];
#pragma unroll
    for (int nt = 0; nt < 8; ++nt)
      b[nt] = *(const bf16x8*)(W2T + (size_t)(nt * 16 + lm) * HDIM + k);
#pragma unroll
    for (int nt = 0; nt < 8; ++nt)
      acc2[nt] = __builtin_amdgcn_mfma_f32_16x16x32_bf16(a, b[nt], acc2[nt], 0, 0, 0);
  }

  // t = relu(acc2 + b2) @ W3 + b3, reduce across 16-lane group, atomic
  float part[4] = {0.0f, 0.0f, 0.0f, 0.0f};
#pragma unroll
  for (int nt = 0; nt < 8; ++nt) {
    int col = nt * 16 + lm;
    float w3v = W3[col];
    float b2v = b2[col];
#pragma unroll
    for (int r = 0; r < 4; ++r)
      part[r] += fmaxf(acc2[nt][r] + b2v, 0.0f) * w3v;
  }
#pragma unroll
  for (int m = 1; m <= 8; m <<= 1)
#pragma unroll
    for (int r = 0; r < 4; ++r)
      part[r] += __shfl_xor(part[r], m, 64);

  if (lm == 0) {
    float b3v = fsmall[512];
    float local = 0.0f;
#pragma unroll
    for (int r = 0; r < 4; ++r) {
      float tval = part[r] + b3v;
      local += shuffled ? expf(tval) : tval;
    }
    atomicAdd(&accum[shuffled ? 1 : 0], local);
  }
}

// ---------------------------------------------------------------------------
// 4) Main GEMM: out[i][j] = 1 - dot(i,j)*inva[i]*invb[j] + 0.01*mi (f32 out).
//    m97 structure: 128x128 tile, BK=64, global_load_lds width-16 into
//    LINEAR LDS [128][64] (dest = wave-uniform base + lane*16 by
//    construction: byte off = t*16 + j*4096), 16x16x32 bf16 MFMA, 2x2 waves.
//    mi is computed from accum here (k_finalize eliminated).
// ---------------------------------------------------------------------------
__global__ __launch_bounds__(256) void k_dist(
    const unsigned short* __restrict__ A,   // xall rows 0..8191
    const unsigned short* __restrict__ B,   // xall rows 8192..16383
    const float* __restrict__ inva, const float* __restrict__ invb,
    const float* __restrict__ accum,
    float* __restrict__ out) {
  __shared__ __attribute__((aligned(16))) unsigned short As[128 * 64];
  __shared__ __attribute__((aligned(16))) unsigned short Bs[128 * 64];
  int t = threadIdx.x;
  int lane = t & 63, wave = t >> 6;
  int lm = lane & 15, lq = lane >> 4;

  // grouped block swizzle: 8 bm-rows per group for A-tile L2 reuse
  int bid = blockIdx.x;
  int rem = bid & 511;
  int bm = (bid >> 9) * 8 + (rem & 7);
  int bn = rem >> 3;
  int wm = wave >> 1, wn = wave & 1;

  f32x4 acc[4][4];
#pragma unroll
  for (int a = 0; a < 4; ++a)
#pragma unroll
    for (int b = 0; b < 4; ++b) acc[a][b] = (f32x4)(0.0f);

  int srow = t >> 3;              // 0..31
  int sc = (t & 7) * 8;           // 0..56 shorts
  const unsigned short* gA = A + (size_t)(bm * 128 + srow) * DDIM + sc;
  const unsigned short* gB = B + (size_t)(bn * 128 + srow) * DDIM + sc;
  unsigned short* lA = As + srow * 64 + sc;
  unsigned short* lB = Bs + srow * 64 + sc;

  for (int kk = 0; kk < 4; ++kk) {
    int k0 = kk * 64;
    __syncthreads();              // prior LDS reads complete before overwrite
#pragma unroll
    for (int j = 0; j < 4; ++j) {
      gl16(gA + k0 + j * 32 * DDIM, lA + j * 32 * 64);
      gl16(gB + k0 + j * 32 * DDIM, lB + j * 32 * 64);
    }
    asm volatile("s_waitcnt vmcnt(0)" ::: "memory");
    __syncthreads();
#pragma unroll
    for (int ko = 0; ko < 64; ko += 32) {
      bf16x8 a[4], b[4];
      int cp = ko + lq * 8;
#pragma unroll
      for (int tm = 0; tm < 4; ++tm)
        a[tm] = *(const bf16x8*)(As + (wm * 64 + tm * 16 + lm) * 64 + cp);
#pragma unroll
      for (int tn = 0; tn < 4; ++tn)
        b[tn] = *(const bf16x8*)(Bs + (wn * 64 + tn * 16 + lm) * 64 + cp);
#pragma unroll
      for (int tm = 0; tm < 4; ++tm)
#pragma unroll
        for (int tn = 0; tn < 4; ++tn)
          acc[tm][tn] = __builtin_amdgcn_mfma_f32_16x16x32_bf16(a[tm], b[tn], acc[tm][tn], 0, 0, 0);
    }
  }

  // mi additive constant (accum finalized by k_critic; stream-ordered)
  float cadd = 0.01f * ((accum[0] - accum[1]) * (1.0f / 8192.0f)
                        - 0.6931471805599453f);
#pragma unroll
  for (int tm = 0; tm < 4; ++tm) {
    int gr0 = bm * 128 + wm * 64 + tm * 16 + lq * 4;
#pragma unroll
    for (int tn = 0; tn < 4; ++tn) {
      int gc = bn * 128 + wn * 64 + tn * 16 + lm;
      float ib = invb[gc];
#pragma unroll
      for (int r = 0; r < 4; ++r)
        out[(size_t)(gr0 + r) * 8192 + gc] =
            1.0f - acc[tm][tn][r] * inva[gr0 + r] * ib + cadd;
    }
  }
}

// ---------------------------------------------------------------------------
extern "C" void kernel_launch(void* const* d_in, const int* in_sizes, int n_in,
                              void* d_out, int out_size, void* d_ws, size_t ws_size,
                              hipStream_t stream) {
  const float* x1 = (const float*)d_in[0];
  const float* x2 = (const float*)d_in[1];
  const float* Wc = (const float*)d_in[2];
  const float* bc = (const float*)d_in[3];
  const float* W1 = (const float*)d_in[4];
  const float* b1 = (const float*)d_in[5];
  const float* W2 = (const float*)d_in[6];
  const float* b2 = (const float*)d_in[7];
  const float* W3 = (const float*)d_in[8];
  const float* b3 = (const float*)d_in[9];
  const int* perm = (const int*)d_in[10];
  float* out = (float*)d_out;

  char* ws = (char*)d_ws;
  unsigned short* xall = (unsigned short*)ws;                          // 8 MB
  unsigned short* xc   = (unsigned short*)(ws + (8u << 20));           // 4 MB
  unsigned short* WcT  = (unsigned short*)(ws + (12u << 20));          // 64 KB
  unsigned short* W1T  = (unsigned short*)(ws + (12u << 20) + 65536);  // 64 KB
  unsigned short* W2T  = (unsigned short*)(ws + (12u << 20) + 131072); // 32 KB
  float* fsmall = (float*)(ws + (12u << 20) + 163840);                 // 2052 B
  float* inva  = (float*)(ws + (12u << 20) + 167936);                  // 32 KB
  float* invb  = (float*)(ws + (12u << 20) + 200704);                  // 32 KB
  float* accum = (float*)(ws + (12u << 20) + 233472);                  // 8 B

  k_prep<<<4096, 256, 0, stream>>>(x1, x2, Wc, bc, W1, b1, W2, b2, W3, b3,
                                   xall, inva, invb, WcT, W1T, W2T, fsmall, accum);
  k_compress<<<256, 256, 0, stream>>>(xall, WcT, fsmall, xc);
  k_critic<<<256, 256, 0, stream>>>(xc, perm, W1T, W2T, fsmall, accum);
  k_dist<<<4096, 256, 0, stream>>>(xall, xall + (size_t)NROWS * DDIM,
                                   inva, invb, accum, out);
}

// Round 4
// 379.247 us; speedup vs baseline: 1.0388x; 1.0010x over previous
//
#include <hip/hip_runtime.h>
#include <hip/hip_bf16.h>
#include <stdint.h>
#include <stddef.h>

// ---------------------------------------------------------------------------
// TSPEnergyFunction: out[i,j] = (1 - cos(x1_i, x2_j)) + 0.01 * mi
// mi = mean(t_xy) - (mean(exp(t_sh)) + ln 2) from a MINE critic.
// f32 in/out; internally bf16 MFMA GEMMs.
// R4 == R2/R3 resubmit (both failed at container acquisition, no kernel
// verdict; code audited twice: no OOB, no deadlock, legal gl_lds mapping):
//  - k_dist: 128x128 tile -> 256x256 tile (8 waves, 512 thr, LDS 64 KB).
//    Halves L2/L3 read traffic (536 -> 256 MB), doubles MFMA:ds_read ratio,
//    same global_load_lds width-16 linear staging (m97 structure).
// ---------------------------------------------------------------------------

typedef __attribute__((ext_vector_type(8))) short bf16x8;
typedef __attribute__((ext_vector_type(4))) float f32x4;

__device__ __forceinline__ float bf2f(unsigned short u) {
  union { unsigned int i; float f; } a; a.i = ((unsigned int)u) << 16; return a.f;
}
__device__ __forceinline__ unsigned short f2bf(float f) {
  union { float f; unsigned int i; } a; a.f = f;
  unsigned int r = a.i + 0x7fffu + ((a.i >> 16) & 1u);  // RNE
  return (unsigned short)(r >> 16);
}

__device__ __forceinline__ void gl16(const unsigned short* g, unsigned short* l) {
  __builtin_amdgcn_global_load_lds(
      (const __attribute__((address_space(1))) void*)g,
      (__attribute__((address_space(3))) void*)l, 16, 0, 0);
}

#define NROWS 8192
#define DDIM 256
#define CDIM 128
#define HDIM 128

// ---------------------------------------------------------------------------
// 1) Prep (merged): all blocks convert rows f32->bf16 + inverse norms;
//    blocks < 32 additionally transpose weights to bf16 and init scalars.
// ---------------------------------------------------------------------------
__global__ __launch_bounds__(256) void k_prep(
    const float* __restrict__ x1, const float* __restrict__ x2,
    const float* __restrict__ Wc, const float* __restrict__ bc,
    const float* __restrict__ W1, const float* __restrict__ b1,
    const float* __restrict__ W2, const float* __restrict__ b2,
    const float* __restrict__ W3, const float* __restrict__ b3,
    unsigned short* __restrict__ xall,
    float* __restrict__ inva, float* __restrict__ invb,
    unsigned short* __restrict__ WcT, unsigned short* __restrict__ W1T,
    unsigned short* __restrict__ W2T, float* __restrict__ fsmall,
    float* __restrict__ accum) {
  int gtid = blockIdx.x * 256 + threadIdx.x;
  int wv = gtid >> 6;            // 0..16383
  int lane = threadIdx.x & 63;
  int first = (wv < NROWS);
  const float* src = first ? x1 : x2;
  float* invp = first ? inva : invb;
  int row = first ? wv : wv - NROWS;
  float4 v = *((const float4*)(src + (size_t)row * DDIM) + lane);
  ushort4 o;
  o.x = f2bf(v.x); o.y = f2bf(v.y); o.z = f2bf(v.z); o.w = f2bf(v.w);
  *((ushort4*)(xall + (size_t)wv * DDIM) + lane) = o;
  float ss = v.x * v.x + v.y * v.y + v.z * v.z + v.w * v.w;
#pragma unroll
  for (int off = 32; off > 0; off >>= 1) ss += __shfl_xor(ss, off, 64);
  if (lane == 0) invp[row] = 1.0f / fmaxf(sqrtf(ss), 1e-8f);

  if (blockIdx.x < 32) {
    int t = blockIdx.x * 256 + threadIdx.x;
    const int T = 32 * 256;
    for (int i = t; i < DDIM * CDIM; i += T) {
      int k = i >> 7, n = i & 127;          // W[k][n] row-major [256][128]
      WcT[n * DDIM + k] = f2bf(Wc[i]);
      W1T[n * DDIM + k] = f2bf(W1[i]);
    }
    for (int i = t; i < HDIM * HDIM; i += T) {
      int k = i >> 7, n = i & 127;
      W2T[n * HDIM + k] = f2bf(W2[i]);
    }
    if (blockIdx.x == 0) {
      int tt = threadIdx.x;
      if (tt < 128) {
        fsmall[tt]       = bc[tt];
        fsmall[128 + tt] = b1[tt];
        fsmall[256 + tt] = b2[tt];
        fsmall[384 + tt] = W3[tt];
      }
      if (tt == 0) {
        fsmall[512] = b3[0];
        accum[0] = 0.0f; accum[1] = 0.0f;
      }
    }
  }
}

// ---------------------------------------------------------------------------
// 2) Compressor: xc[v] = xall[v] @ Wc + bc, bf16 out.
//    256 blocks x 64 rows (16 rows/wave).
// ---------------------------------------------------------------------------
__global__ __launch_bounds__(256) void k_compress(
    const unsigned short* __restrict__ xall,
    const unsigned short* __restrict__ WcT,
    const float* __restrict__ fsmall,
    unsigned short* __restrict__ xc) {
  int lane = threadIdx.x & 63, wave = threadIdx.x >> 6;
  int lm = lane & 15, lq = lane >> 4;
  int r0 = blockIdx.x * 64 + wave * 16;

  f32x4 acc[8];
#pragma unroll
  for (int b = 0; b < 8; ++b) acc[b] = (f32x4)(0.0f);

  for (int ks = 0; ks < 8; ++ks) {
    int k = ks * 32 + lq * 8;
    bf16x8 a = *(const bf16x8*)(xall + (size_t)(r0 + lm) * DDIM + k);
    bf16x8 b[8];
#pragma unroll
    for (int nt = 0; nt < 8; ++nt)
      b[nt] = *(const bf16x8*)(WcT + (size_t)(nt * 16 + lm) * DDIM + k);
#pragma unroll
    for (int nt = 0; nt < 8; ++nt)
      acc[nt] = __builtin_amdgcn_mfma_f32_16x16x32_bf16(a, b[nt], acc[nt], 0, 0, 0);
  }

  int row = r0 + lq * 4;
#pragma unroll
  for (int nt = 0; nt < 8; ++nt) {
    int col = nt * 16 + lm;
    float bcv = fsmall[col];
#pragma unroll
    for (int r = 0; r < 4; ++r)
      xc[(size_t)(row + r) * CDIM + col] = f2bf(acc[nt][r] + bcv);
  }
}

// ---------------------------------------------------------------------------
// 3) Critic: 16384 virtual rows (first 8192 joint, last 8192 shuffled).
//    256 blocks x 64 vrows (16/wave); accumulate sum(t)/sum(exp(t)).
// ---------------------------------------------------------------------------
__global__ __launch_bounds__(256) void k_critic(
    const unsigned short* __restrict__ xc, const int* __restrict__ perm,
    const unsigned short* __restrict__ W1T, const unsigned short* __restrict__ W2T,
    const float* __restrict__ fsmall, float* __restrict__ accum) {
  __shared__ __attribute__((aligned(16))) unsigned short h1buf[4][16][136];
  const float* b1 = fsmall + 128;
  const float* b2 = fsmall + 256;
  const float* W3 = fsmall + 384;
  int lane = threadIdx.x & 63, wave = threadIdx.x >> 6;
  int lm = lane & 15, lq = lane >> 4;
  int v0 = blockIdx.x * 64 + wave * 16;
  bool shuffled = (blockIdx.x * 64 >= NROWS);   // uniform per block

  f32x4 acc[8];
#pragma unroll
  for (int b = 0; b < 8; ++b) acc[b] = (f32x4)(0.0f);

  // layer 1: K = 256 (two 128-halves of z)
  for (int ks = 0; ks < 8; ++ks) {
    int k = ks * 32 + lq * 8;
    int i = (v0 + lm) & (NROWS - 1);
    const unsigned short* zp;
    if (k < CDIM) {
      zp = xc + (size_t)i * CDIM + k;
    } else {
      int j = shuffled ? perm[i] : i;
      zp = xc + (size_t)(NROWS + j) * CDIM + (k - CDIM);
    }
    bf16x8 a = *(const bf16x8*)zp;
    bf16x8 b[8];
#pragma unroll
    for (int nt = 0; nt < 8; ++nt)
      b[nt] = *(const bf16x8*)(W1T + (size_t)(nt * 16 + lm) * DDIM + k);
#pragma unroll
    for (int nt = 0; nt < 8; ++nt)
      acc[nt] = __builtin_amdgcn_mfma_f32_16x16x32_bf16(a, b[nt], acc[nt], 0, 0, 0);
  }

  // h1 = relu(acc + b1) -> LDS (per-wave buffer)
#pragma unroll
  for (int nt = 0; nt < 8; ++nt) {
    int col = nt * 16 + lm;
    float bv = b1[col];
#pragma unroll
    for (int r = 0; r < 4; ++r)
      h1buf[wave][lq * 4 + r][col] = f2bf(fmaxf(acc[nt][r] + bv, 0.0f));
  }
  __syncthreads();

  // layer 2: K = 128
  f32x4 acc2[8];
#pragma unroll
  for (int b = 0; b < 8; ++b) acc2[b] = (f32x4)(0.0f);
  for (int ks = 0; ks < 4; ++ks) {
    int k = ks * 32 + lq * 8;
    bf16x8 a = *(const bf16x8*)&h1buf[wave][lm][k];
    bf16x8 b[8];
#pragma unroll
    for (int nt = 0; nt < 8; ++nt)
      b[nt] = *(const bf16x8*)(W2T + (size_t)(nt * 16 + lm) * HDIM + k);
#pragma unroll
    for (int nt = 0; nt < 8; ++nt)
      acc2[nt] = __builtin_amdgcn_mfma_f32_16x16x32_bf16(a, b[nt], acc2[nt], 0, 0, 0);
  }

  // t = relu(acc2 + b2) @ W3 + b3, reduce across 16-lane group, atomic
  float part[4] = {0.0f, 0.0f, 0.0f, 0.0f};
#pragma unroll
  for (int nt = 0; nt < 8; ++nt) {
    int col = nt * 16 + lm;
    float w3v = W3[col];
    float b2v = b2[col];
#pragma unroll
    for (int r = 0; r < 4; ++r)
      part[r] += fmaxf(acc2[nt][r] + b2v, 0.0f) * w3v;
  }
#pragma unroll
  for (int m = 1; m <= 8; m <<= 1)
#pragma unroll
    for (int r = 0; r < 4; ++r)
      part[r] += __shfl_xor(part[r], m, 64);

  if (lm == 0) {
    float b3v = fsmall[512];
    float local = 0.0f;
#pragma unroll
    for (int r = 0; r < 4; ++r) {
      float tval = part[r] + b3v;
      local += shuffled ? expf(tval) : tval;
    }
    atomicAdd(&accum[shuffled ? 1 : 0], local);
  }
}

// ---------------------------------------------------------------------------
// 4) Main GEMM: out[i][j] = 1 - dot(i,j)*inva[i]*invb[j] + 0.01*mi (f32 out).
//    256x256 tile, BK=64, 8 waves (512 thr), LDS 64 KB single-buffered,
//    global_load_lds width-16 into LINEAR LDS [256][64]
//    (byte dest = t*16 + j*8192: wave-uniform base + lane*16).
//    Wave tile 128x64: 8x4 fragments of 16x16x32 bf16 MFMA.
// ---------------------------------------------------------------------------
__global__ __launch_bounds__(512, 2) void k_dist(
    const unsigned short* __restrict__ A,   // xall rows 0..8191
    const unsigned short* __restrict__ B,   // xall rows 8192..16383
    const float* __restrict__ inva, const float* __restrict__ invb,
    const float* __restrict__ accum,
    float* __restrict__ out) {
  __shared__ __attribute__((aligned(16))) unsigned short As[256 * 64];
  __shared__ __attribute__((aligned(16))) unsigned short Bs[256 * 64];
  int t = threadIdx.x;
  int lane = t & 63, wave = t >> 6;
  int lm = lane & 15, lq = lane >> 4;

  // grouped block swizzle: 8 bm-rows per group for A-panel L2 reuse
  int bid = blockIdx.x;            // 0..1023; grid is 32x32 tiles
  int rem = bid & 255;
  int bm = (bid >> 8) * 8 + (rem & 7);
  int bn = rem >> 3;
  int wm = wave >> 2, wn = wave & 3;   // wave tile: rows wm*128+, cols wn*64+

  f32x4 acc[8][4];
#pragma unroll
  for (int a = 0; a < 8; ++a)
#pragma unroll
    for (int b = 0; b < 4; ++b) acc[a][b] = (f32x4)(0.0f);

  int srow = t >> 3;              // 0..63
  int sc = (t & 7) * 8;           // 0..56 shorts
  const unsigned short* gA = A + (size_t)(bm * 256 + srow) * DDIM + sc;
  const unsigned short* gB = B + (size_t)(bn * 256 + srow) * DDIM + sc;
  unsigned short* lA = As + srow * 64 + sc;
  unsigned short* lB = Bs + srow * 64 + sc;

  for (int kk = 0; kk < 4; ++kk) {
    int k0 = kk * 64;
    __syncthreads();              // prior LDS reads complete before overwrite
#pragma unroll
    for (int j = 0; j < 4; ++j) {
      gl16(gA + k0 + (size_t)j * 64 * DDIM, lA + j * 64 * 64);
      gl16(gB + k0 + (size_t)j * 64 * DDIM, lB + j * 64 * 64);
    }
    asm volatile("s_waitcnt vmcnt(0)" ::: "memory");
    __syncthreads();
#pragma unroll
    for (int ko = 0; ko < 64; ko += 32) {
      bf16x8 a[8], b[4];
      int cp = ko + lq * 8;
#pragma unroll
      for (int tm = 0; tm < 8; ++tm)
        a[tm] = *(const bf16x8*)(As + (wm * 128 + tm * 16 + lm) * 64 + cp);
#pragma unroll
      for (int tn = 0; tn < 4; ++tn)
        b[tn] = *(const bf16x8*)(Bs + (wn * 64 + tn * 16 + lm) * 64 + cp);
#pragma unroll
      for (int tm = 0; tm < 8; ++tm)
#pragma unroll
        for (int tn = 0; tn < 4; ++tn)
          acc[tm][tn] = __builtin_amdgcn_mfma_f32_16x16x32_bf16(a[tm], b[tn], acc[tm][tn], 0, 0, 0);
    }
  }

  // mi additive constant (accum finalized by k_critic; stream-ordered)
  float cadd = 0.01f * ((accum[0] - accum[1]) * (1.0f / 8192.0f)
                        - 0.6931471805599453f);
#pragma unroll
  for (int tm = 0; tm < 8; ++tm) {
    int gr0 = bm * 256 + wm * 128 + tm * 16 + lq * 4;
    float ia[4];
#pragma unroll
    for (int r = 0; r < 4; ++r) ia[r] = inva[gr0 + r];
#pragma unroll
    for (int tn = 0; tn < 4; ++tn) {
      int gc = bn * 256 + wn * 64 + tn * 16 + lm;
      float ib = invb[gc];
#pragma unroll
      for (int r = 0; r < 4; ++r)
        out[(size_t)(gr0 + r) * 8192 + gc] =
            1.0f - acc[tm][tn][r] * ia[r] * ib + cadd;
    }
  }
}

// ---------------------------------------------------------------------------
extern "C" void kernel_launch(void* const* d_in, const int* in_sizes, int n_in,
                              void* d_out, int out_size, void* d_ws, size_t ws_size,
                              hipStream_t stream) {
  const float* x1 = (const float*)d_in[0];
  const float* x2 = (const float*)d_in[1];
  const float* Wc = (const float*)d_in[2];
  const float* bc = (const float*)d_in[3];
  const float* W1 = (const float*)d_in[4];
  const float* b1 = (const float*)d_in[5];
  const float* W2 = (const float*)d_in[6];
  const float* b2 = (const float*)d_in[7];
  const float* W3 = (const float*)d_in[8];
  const float* b3 = (const float*)d_in[9];
  const int* perm = (const int*)d_in[10];
  float* out = (float*)d_out;

  char* ws = (char*)d_ws;
  unsigned short* xall = (unsigned short*)ws;                          // 8 MB
  unsigned short* xc   = (unsigned short*)(ws + (8u << 20));           // 4 MB
  unsigned short* WcT  = (unsigned short*)(ws + (12u << 20));          // 64 KB
  unsigned short* W1T  = (unsigned short*)(ws + (12u << 20) + 65536);  // 64 KB
  unsigned short* W2T  = (unsigned short*)(ws + (12u << 20) + 131072); // 32 KB
  float* fsmall = (float*)(ws + (12u << 20) + 163840);                 // 2052 B
  float* inva  = (float*)(ws + (12u << 20) + 167936);                  // 32 KB
  float* invb  = (float*)(ws + (12u << 20) + 200704);                  // 32 KB
  float* accum = (float*)(ws + (12u << 20) + 233472);                  // 8 B

  k_prep<<<4096, 256, 0, stream>>>(x1, x2, Wc, bc, W1, b1, W2, b2, W3, b3,
                                   xall, inva, invb, WcT, W1T, W2T, fsmall, accum);
  k_compress<<<256, 256, 0, stream>>>(xall, WcT, fsmall, xc);
  k_critic<<<256, 256, 0, stream>>>(xc, perm, W1T, W2T, fsmall, accum);
  k_dist<<<1024, 512, 0, stream>>>(xall, xall + (size_t)NROWS * DDIM,
                                   inva, invb, accum, out);
}